// Round 7
// baseline (655.797 us; speedup 1.0000x reference)
//
#include <hip/hip_runtime.h>

typedef unsigned short u16;
typedef unsigned int   u32;
typedef __bf16 bf16x8 __attribute__((ext_vector_type(8)));
typedef u16    u16x8  __attribute__((ext_vector_type(8)));
typedef float  f32x4  __attribute__((ext_vector_type(4)));

#define DI static __device__ __forceinline__

DI float b2f(u16 u){ union { u32 i; float f; } c; c.i = ((u32)u) << 16; return c.f; }
DI u16 f2b(float f){ return __builtin_bit_cast(u16, (__bf16)f); }   // HW RNE cvt
DI float eluf(float x){ return x > 0.f ? x : (__expf(x) - 1.f); }
DI float sigf(float x){ return 1.f / (1.f + __expf(-x)); }
DI f32x4 mfma16(bf16x8 a, bf16x8 b, f32x4 c){
  return __builtin_amdgcn_mfma_f32_16x16x32_bf16(a, b, c, 0, 0, 0);
}
DI bf16x8 ldb(const u16* p){ return *(const bf16x8*)p; }

// ---------------------------------------------------------------------------
// k_pack: blocks 0..1023 pack x (LDS-staged, coalesced both sides);
// blocks 1024..1376 pack weights via LDS-staged 32x256 tiles (coalesced
// float4 reads -- kills the 16x line-fetch amplification of per-lane strided
// reads).  Fragment layout (all): elem = W[k=kc*32+(lane>>4)*8+j][n=nb*16+(lane&15)]
// ---------------------------------------------------------------------------
DI void stage_tile(const float* __restrict__ W, int t, u16* sT){
  #pragma unroll
  for (int u = 0; u < 8; u++){
    int c = u * 256 + t, row = c >> 6, colf = (c & 63) * 4;
    float4 v4 = *(const float4*)&W[row * 256 + colf];
    u16 a = f2b(v4.x), b = f2b(v4.y), cc = f2b(v4.z), d = f2b(v4.w);
    uint2 pk; pk.x = (u32)a | ((u32)b << 16); pk.y = (u32)cc | ((u32)d << 16);
    *(uint2*)&sT[row * 260 + colf] = pk;
  }
}
DI void emit_tile(const u16* sT, int t, u16* dstbase, int kc, int KC){
  #pragma unroll
  for (int u = 0; u < 4; u++){
    int g = u * 256 + t, nb = g >> 6, lane = g & 63, ln = lane & 15, q = lane >> 4;
    u16x8 tv;
    #pragma unroll
    for (int j = 0; j < 8; j++) tv[j] = sT[(q * 8 + j) * 260 + nb * 16 + ln];
    *(uint4*)&dstbase[((size_t)(nb * KC + kc)) * 512 + lane * 8] = __builtin_bit_cast(uint4, tv);
  }
}

__global__ __launch_bounds__(256) void k_pack(
    const float* __restrict__ x,
    const float* __restrict__ wfc1, const float* __restrict__ wskip,
    const float* __restrict__ vfc1, const float* __restrict__ vfc2,
    const float* __restrict__ vgate, const float* __restrict__ vskip,
    u16* __restrict__ pX, u16* __restrict__ pW1, u16* __restrict__ pF1,
    u16* __restrict__ pSk, u16* __restrict__ pF2, u16* __restrict__ pGa)
{
  __shared__ u16 sX[16 * 1032];     // 33024 B; also used as tile/skip stage
  const int t = threadIdx.x;
  if (blockIdx.x < 1024){
    const int rb = blockIdx.x;
    const float* xp = x + (size_t)rb * 16384;
    #pragma unroll
    for (int it = 0; it < 16; it++){
      float4 v4 = *(const float4*)&xp[it * 1024 + t * 4];
      u16 t0 = f2b(v4.x), t1 = f2b(v4.y), t2 = f2b(v4.z), t3 = f2b(v4.w);
      uint2 pk; pk.x = (u32)t0 | ((u32)t1 << 16); pk.y = (u32)t2 | ((u32)t3 << 16);
      *(uint2*)&sX[it * 1032 + t * 4] = pk;
    }
    __syncthreads();
    u16* dst = pX + (size_t)rb * 16384;
    #pragma unroll
    for (int u = 0; u < 8; u++){
      int c = u * 256 + t;
      int kc = c >> 6, lane = c & 63, ln = lane & 15, q = lane >> 4;
      u16x8 v = *(const u16x8*)&sX[ln * 1032 + kc * 32 + q * 8];
      *(uint4*)&dst[kc * 512 + lane * 8] = __builtin_bit_cast(uint4, v);
    }
    return;
  }
  const int wb = blockIdx.x - 1024;   // 0..352
  if (wb == 32){
    // wskip [1024][16] -> pW1 nb=16 (kc 0..31)
    #pragma unroll
    for (int u = 0; u < 64; u++){
      int c = u * 256 + t, row = c >> 2, colf = (c & 3) * 4;
      float4 v4 = *(const float4*)&wskip[row * 16 + colf];
      u16 a = f2b(v4.x), b = f2b(v4.y), cc = f2b(v4.z), d = f2b(v4.w);
      uint2 pk; pk.x = (u32)a | ((u32)b << 16); pk.y = (u32)cc | ((u32)d << 16);
      *(uint2*)&sX[row * 16 + colf] = pk;
    }
    __syncthreads();
    #pragma unroll
    for (int u = 0; u < 8; u++){
      int g = u * 256 + t, kc = g >> 6, lane = g & 63, ln = lane & 15, q = lane >> 4;
      u16x8 tv;
      #pragma unroll
      for (int j = 0; j < 8; j++) tv[j] = sX[(kc * 32 + q * 8 + j) * 16 + ln];
      *(uint4*)&pW1[((size_t)(16 * 32 + kc)) * 512 + lane * 8] = __builtin_bit_cast(uint4, tv);
    }
    return;
  }
  const float* src; u16* dstbase; int kc, KC;
  if (wb < 32){                       // wfc1 [1024][256] -> pW1 nb 0..15
    kc = wb; KC = 32; src = wfc1 + (size_t)kc * 32 * 256; dstbase = pW1;
  } else if (wb < 65){                // vfc1 [16][64][256] -> pF1
    int idx = wb - 33, v = idx >> 1, ks = idx & 1;
    kc = ks; KC = 2; src = vfc1 + ((size_t)v * 64 + ks * 32) * 256;
    dstbase = pF1 + (size_t)v * 32 * 512;
  } else if (wb < 97){                // vskip -> pSk
    int idx = wb - 65, v = idx >> 1, ks = idx & 1;
    kc = ks; KC = 2; src = vskip + ((size_t)v * 64 + ks * 32) * 256;
    dstbase = pSk + (size_t)v * 32 * 512;
  } else if (wb < 225){               // vfc2 [16][256][256] -> pF2
    int idx = wb - 97, v = idx >> 3, kk = idx & 7;
    kc = kk; KC = 8; src = vfc2 + ((size_t)v * 256 + kk * 32) * 256;
    dstbase = pF2 + (size_t)v * 128 * 512;
  } else {                            // vgate -> pGa
    int idx = wb - 225, v = idx >> 3, kk = idx & 7;
    kc = kk; KC = 8; src = vgate + ((size_t)v * 256 + kk * 32) * 256;
    dstbase = pGa + (size_t)v * 128 * 512;
  }
  stage_tile(src, t, sX);
  __syncthreads();
  emit_tile(sX, t, dstbase, kc, KC);
}

// ---------------------------------------------------------------------------
// Fused kernel: weight-GRN prologue (w -> sWt, duplicated per v-half) +
// round-5 2-barrier v-loop over HALF the variables.
// Grid 1024: xcd = bid&7; vhalf = xcd>>2; rowblk = (bid>>3)*4 + (bid&3).
//  -> XCDs 0-3 run v 0..7, XCDs 4-7 run v 8..15: per-XCD weight working set
//     = pW1(1.1MB) + half weights(2.65MB) = 3.75MB <= 4MB L2.
// vhalf 0 -> plain store to part (ws); vhalf 1 -> plain store to out;
// k_reduce then does out += part. No atomics anywhere.
// LDS 35840 B (W2 staged bf16), VGPR capped 64 via (512,8) -> 4 blocks/CU.
// ---------------------------------------------------------------------------
__global__ __launch_bounds__(512, 8) void k_fused(
    const u16* __restrict__ pX, const u16* __restrict__ pW1,
    const u16* __restrict__ pF1, const u16* __restrict__ pSk,
    const u16* __restrict__ pF2, const u16* __restrict__ pGa,
    const float* __restrict__ wb1, const float* __restrict__ W2,
    const float* __restrict__ wb2, const float* __restrict__ Wg,
    const float* __restrict__ wbg, const float* __restrict__ wbs,
    const float* __restrict__ b1, const float* __restrict__ b2,
    const float* __restrict__ bg, const float* __restrict__ bs,
    float* __restrict__ part, float* __restrict__ out)
{
  __shared__ __align__(16) char smem[35840];
  u16*   sHh = (u16*)smem;                     // 16896: prologue h / v-loop hv
  u16*   sHy = (u16*)(smem + 16896);           // 16896: v-loop yv
  // prologue aliases inside sHy region:
  u16*   sW2 = (u16*)(smem + 16896);           // 8192: W2 bf16 [256][16]
  float* sR  = (float*)(smem + 16896 + 8192);  // 2048
  float* sY  = (float*)(smem + 16896 + 10240); // 2048
  float* sWg = (float*)(smem + 16896 + 12288); // 1024
  float* sWt = (float*)(smem + 33792);         // 2048, persists

  const int tid  = threadIdx.x;
  const int lane = tid & 63;
  const int wid  = tid >> 6;
  const int ln   = lane & 15;
  const int q    = lane >> 4;
  const int bid  = blockIdx.x;
  const int xcd  = bid & 7;
  const int vhalf = xcd >> 2;                  // XCD-partitioned v-half
  const int rowblk = (bid >> 3) * 4 + (bid & 3);
  const int row0 = rowblk * 32;
  const int rb0  = rowblk * 2;
  const int nb0  = wid * 2;
  const int v0   = vhalf * 8;

  // ===================== prologue: weight GRN -> sWt =====================
  {
    const int ncnt = (wid == 7) ? 3 : 2;
    // stage W2 bf16 + Wg fp32
    {
      const float* wp = &W2[tid * 8];
      float4 lo = *(const float4*)wp, hi = *(const float4*)(wp + 4);
      u16x8 tv;
      tv[0]=f2b(lo.x); tv[1]=f2b(lo.y); tv[2]=f2b(lo.z); tv[3]=f2b(lo.w);
      tv[4]=f2b(hi.x); tv[5]=f2b(hi.y); tv[6]=f2b(hi.z); tv[7]=f2b(hi.w);
      *(uint4*)&sW2[tid * 8] = __builtin_bit_cast(uint4, tv);
      if (tid < 256) sWg[tid] = Wg[tid];
    }

    f32x4 acc[2][3];
    #pragma unroll
    for (int mb = 0; mb < 2; mb++)
      #pragma unroll
      for (int i = 0; i < 3; i++){ acc[mb][i][0]=0.f; acc[mb][i][1]=0.f; acc[mb][i][2]=0.f; acc[mb][i][3]=0.f; }

    for (int kc = 0; kc < 32; kc++){
      bf16x8 a[2];
      #pragma unroll
      for (int mb = 0; mb < 2; mb++)
        a[mb] = ldb(&pX[((size_t)(rb0 + mb) * 32 + kc) * 512 + lane * 8]);
      #pragma unroll
      for (int i = 0; i < 3; i++){
        if (i < ncnt){
          bf16x8 b = ldb(&pW1[(size_t)((nb0 + i) * 32 + kc) * 512 + lane * 8]);
          #pragma unroll
          for (int mb = 0; mb < 2; mb++) acc[mb][i] = mfma16(a[mb], b, acc[mb][i]);
        }
      }
    }

    #pragma unroll
    for (int i = 0; i < 3; i++){
      if (i < ncnt){
        int nb = nb0 + i;
        int col = nb * 16 + ln;
        float vb = (nb < 16) ? wb1[col] : wbs[ln];
        #pragma unroll
        for (int mb = 0; mb < 2; mb++){
          #pragma unroll
          for (int r = 0; r < 4; r++){
            int lr = mb * 16 + q * 4 + r;
            float v = acc[mb][i][r] + vb;
            if (nb < 16) sHh[lr * 264 + col] = f2b(eluf(v));
            else         sR[lr * 16 + ln] = v;
          }
        }
      }
    }
    __syncthreads();

    // y = h @ W2 + b2  (W2 bf16 in LDS)
    {
      int r = tid >> 4, j = tid & 15;
      float a0 = wb2[j];
      #pragma unroll 4
      for (int kb = 0; kb < 32; kb++){
        u16x8 h8 = *(const u16x8*)&sHh[r * 264 + kb * 8];
        #pragma unroll
        for (int u = 0; u < 8; u++)
          a0 += b2f(h8[u]) * b2f(sW2[(kb * 8 + u) * 16 + j]);
      }
      sY[r * 16 + j] = a0;
    }
    __syncthreads();

    // gate = sigmoid(y @ Wg + bg) -> sWt (scratch)
    {
      int r = tid >> 4, j = tid & 15;
      float g0 = wbg[j];
      #pragma unroll
      for (int k = 0; k < 16; k++)
        g0 += sY[r * 16 + k] * sWg[k * 16 + j];
      sWt[r * 16 + j] = sigf(g0);
    }
    __syncthreads();

    // softmax over 16 -> sWt
    if (tid < 32){
      int r = tid;
      float l[16]; float m = -1e30f;
      #pragma unroll
      for (int j = 0; j < 16; j++){
        float v = sR[r * 16 + j] + sWt[r * 16 + j] * sY[r * 16 + j];
        l[j] = v; m = fmaxf(m, v);
      }
      float s = 0.f;
      #pragma unroll
      for (int j = 0; j < 16; j++){ l[j] = __expf(l[j] - m); s += l[j]; }
      float inv = 1.f / s;
      #pragma unroll
      for (int j = 0; j < 16; j++) sWt[r * 16 + j] = l[j] * inv;
    }
    __syncthreads();
  }

  // ===================== v-loop over this block's 8 variables =====================
  f32x4 z[2][2];
  #pragma unroll
  for (int mb = 0; mb < 2; mb++)
    #pragma unroll
    for (int i = 0; i < 2; i++){ z[mb][i][0]=0.f; z[mb][i][1]=0.f; z[mb][i][2]=0.f; z[mb][i][3]=0.f; }

  #pragma unroll 1
  for (int vi = 0; vi < 8; vi++){
    const int v = v0 + vi;
    bf16x8 a0[2], a1[2];
    #pragma unroll
    for (int mb = 0; mb < 2; mb++){
      const u16* xp = &pX[((size_t)(rb0 + mb) * 32 + v * 2) * 512 + lane * 8];
      a0[mb] = ldb(xp);
      a1[mb] = ldb(xp + 512);
    }
    float wv[2][4];
    #pragma unroll
    for (int mb = 0; mb < 2; mb++)
      #pragma unroll
      for (int r = 0; r < 4; r++) wv[mb][r] = sWt[(mb * 16 + q * 4 + r) * 16 + v];

    // ---- phase 1a: hv = elu(Xv @ W1v + b1) -> sHh
    f32x4 hacc[2][2];
    #pragma unroll
    for (int mb = 0; mb < 2; mb++)
      #pragma unroll
      for (int i = 0; i < 2; i++){ hacc[mb][i][0]=0.f; hacc[mb][i][1]=0.f; hacc[mb][i][2]=0.f; hacc[mb][i][3]=0.f; }
    #pragma unroll
    for (int ks = 0; ks < 2; ks++){
      bf16x8 B0 = ldb(&pF1[(size_t)((v * 16 + nb0) * 2 + ks) * 512 + lane * 8]);
      bf16x8 B1 = ldb(&pF1[(size_t)((v * 16 + nb0 + 1) * 2 + ks) * 512 + lane * 8]);
      #pragma unroll
      for (int mb = 0; mb < 2; mb++){
        bf16x8 a = ks ? a1[mb] : a0[mb];
        hacc[mb][0] = mfma16(a, B0, hacc[mb][0]);
        hacc[mb][1] = mfma16(a, B1, hacc[mb][1]);
      }
    }
    #pragma unroll
    for (int i = 0; i < 2; i++){
      int col = (nb0 + i) * 16 + ln;
      float vb = b1[v * 256 + col];
      #pragma unroll
      for (int mb = 0; mb < 2; mb++)
        #pragma unroll
        for (int r = 0; r < 4; r++)
          sHh[(mb * 16 + q * 4 + r) * 264 + col] = f2b(eluf(hacc[mb][i][r] + vb));
    }

    // ---- phase 1b: rv = Xv @ Wsv + bs ; z += wv * rv
    f32x4 racc[2][2];
    #pragma unroll
    for (int mb = 0; mb < 2; mb++)
      #pragma unroll
      for (int i = 0; i < 2; i++){ racc[mb][i][0]=0.f; racc[mb][i][1]=0.f; racc[mb][i][2]=0.f; racc[mb][i][3]=0.f; }
    #pragma unroll
    for (int ks = 0; ks < 2; ks++){
      bf16x8 B0 = ldb(&pSk[(size_t)((v * 16 + nb0) * 2 + ks) * 512 + lane * 8]);
      bf16x8 B1 = ldb(&pSk[(size_t)((v * 16 + nb0 + 1) * 2 + ks) * 512 + lane * 8]);
      #pragma unroll
      for (int mb = 0; mb < 2; mb++){
        bf16x8 a = ks ? a1[mb] : a0[mb];
        racc[mb][0] = mfma16(a, B0, racc[mb][0]);
        racc[mb][1] = mfma16(a, B1, racc[mb][1]);
      }
    }
    #pragma unroll
    for (int i = 0; i < 2; i++){
      float vb = bs[v * 256 + (nb0 + i) * 16 + ln];
      #pragma unroll
      for (int mb = 0; mb < 2; mb++)
        #pragma unroll
        for (int r = 0; r < 4; r++) z[mb][i][r] += wv[mb][r] * (racc[mb][i][r] + vb);
    }
    __syncthreads();   // B1: hv visible; prev-v yv reads done before sHy rewrite

    // ---- phase 2: yv = hv @ W2v + b2  (read sHh, write sHy)
    f32x4 yacc[2][2];
    #pragma unroll
    for (int mb = 0; mb < 2; mb++)
      #pragma unroll
      for (int i = 0; i < 2; i++){ yacc[mb][i][0]=0.f; yacc[mb][i][1]=0.f; yacc[mb][i][2]=0.f; yacc[mb][i][3]=0.f; }
    #pragma unroll
    for (int kc = 0; kc < 8; kc++){
      bf16x8 B0 = ldb(&pF2[(size_t)((v * 16 + nb0) * 8 + kc) * 512 + lane * 8]);
      bf16x8 B1 = ldb(&pF2[(size_t)((v * 16 + nb0 + 1) * 8 + kc) * 512 + lane * 8]);
      #pragma unroll
      for (int mb = 0; mb < 2; mb++){
        bf16x8 ah = *(const bf16x8*)&sHh[(mb * 16 + ln) * 264 + kc * 32 + q * 8];
        yacc[mb][0] = mfma16(ah, B0, yacc[mb][0]);
        yacc[mb][1] = mfma16(ah, B1, yacc[mb][1]);
      }
    }
    f32x4 ysave[2][2];
    #pragma unroll
    for (int i = 0; i < 2; i++){
      int col = (nb0 + i) * 16 + ln;
      float vb = b2[v * 256 + col];
      #pragma unroll
      for (int mb = 0; mb < 2; mb++)
        #pragma unroll
        for (int r = 0; r < 4; r++){
          float yy = yacc[mb][i][r] + vb;
          ysave[mb][i][r] = yy;
          sHy[(mb * 16 + q * 4 + r) * 264 + col] = f2b(yy);
        }
    }
    __syncthreads();   // B2: yv visible; all hv reads done before next-v rewrite

    // ---- phase 3: gv = sigmoid(yv @ Wgv + bg); z += wv * gv * yv
    f32x4 gacc[2][2];
    #pragma unroll
    for (int mb = 0; mb < 2; mb++)
      #pragma unroll
      for (int i = 0; i < 2; i++){ gacc[mb][i][0]=0.f; gacc[mb][i][1]=0.f; gacc[mb][i][2]=0.f; gacc[mb][i][3]=0.f; }
    #pragma unroll
    for (int kc = 0; kc < 8; kc++){
      bf16x8 B0 = ldb(&pGa[(size_t)((v * 16 + nb0) * 8 + kc) * 512 + lane * 8]);
      bf16x8 B1 = ldb(&pGa[(size_t)((v * 16 + nb0 + 1) * 8 + kc) * 512 + lane * 8]);
      #pragma unroll
      for (int mb = 0; mb < 2; mb++){
        bf16x8 ah = *(const bf16x8*)&sHy[(mb * 16 + ln) * 264 + kc * 32 + q * 8];
        gacc[mb][0] = mfma16(ah, B0, gacc[mb][0]);
        gacc[mb][1] = mfma16(ah, B1, gacc[mb][1]);
      }
    }
    #pragma unroll
    for (int i = 0; i < 2; i++){
      float vb = bg[v * 256 + (nb0 + i) * 16 + ln];
      #pragma unroll
      for (int mb = 0; mb < 2; mb++)
        #pragma unroll
        for (int r = 0; r < 4; r++)
          z[mb][i][r] += wv[mb][r] * sigf(gacc[mb][i][r] + vb) * ysave[mb][i][r];
    }
  }

  // store partial z: vhalf 0 -> part (ws), vhalf 1 -> out. Plain stores.
  float* dst = vhalf ? out : part;
  #pragma unroll
  for (int i = 0; i < 2; i++){
    int col = (nb0 + i) * 16 + ln;
    #pragma unroll
    for (int mb = 0; mb < 2; mb++)
      #pragma unroll
      for (int r = 0; r < 4; r++)
        dst[(size_t)(row0 + mb * 16 + q * 4 + r) * 256 + col] = z[mb][i][r];
  }
}

// ---------------------------------------------------------------------------
// k_reduce: out += part  (4,194,304 floats; 4096 blocks x 256 thr x float4)
// ---------------------------------------------------------------------------
__global__ __launch_bounds__(256) void k_reduce(
    const float* __restrict__ part, float* __restrict__ out)
{
  size_t i = ((size_t)blockIdx.x * 256 + threadIdx.x) * 4;
  float4 a = *(const float4*)&part[i];
  float4 b = *(const float4*)&out[i];
  b.x += a.x; b.y += a.y; b.z += a.z; b.w += a.w;
  *(float4*)&out[i] = b;
}

// ---------------------------------------------------------------------------
extern "C" void kernel_launch(void* const* d_in, const int* in_sizes, int n_in,
                              void* d_out, int out_size, void* d_ws, size_t ws_size,
                              hipStream_t stream)
{
  const float* x     = (const float*)d_in[0];
  const float* wfc1w = (const float*)d_in[1];
  const float* wfc1b = (const float*)d_in[2];
  const float* wfc2w = (const float*)d_in[3];
  const float* wfc2b = (const float*)d_in[4];
  const float* wgw   = (const float*)d_in[5];
  const float* wgb   = (const float*)d_in[6];
  const float* wsw   = (const float*)d_in[7];
  const float* wsb   = (const float*)d_in[8];
  const float* vfc1w = (const float*)d_in[9];
  const float* vfc1b = (const float*)d_in[10];
  const float* vfc2w = (const float*)d_in[11];
  const float* vfc2b = (const float*)d_in[12];
  const float* vgw   = (const float*)d_in[13];
  const float* vgb   = (const float*)d_in[14];
  const float* vsw   = (const float*)d_in[15];
  const float* vsb   = (const float*)d_in[16];

  u16* ws   = (u16*)d_ws;
  u16* pX   = ws;                      // 16777216 u16 (32 MB)
  u16* pW1  = pX + 16777216;           // 278528 u16
  u16* pF1  = pW1 + 278528;            // 262144
  u16* pSk  = pF1 + 262144;            // 262144
  u16* pF2  = pSk + 262144;            // 1048576
  u16* pGa  = pF2 + 1048576;           // 1048576
  float* part = (float*)(pGa + 1048576); // 4194304 fp32 (16 MB)

  k_pack<<<dim3(1377), dim3(256), 0, stream>>>(
      x, wfc1w, wsw, vfc1w, vfc2w, vgw, vsw, pX, pW1, pF1, pSk, pF2, pGa);

  k_fused<<<dim3(1024), dim3(512), 0, stream>>>(
      pX, pW1, pF1, pSk, pF2, pGa,
      wfc1b, wfc2w, wfc2b, wgw, wgb, wsb,
      vfc1b, vfc2b, vgb, vsb, part, (float*)d_out);

  k_reduce<<<dim3(4096), dim3(256), 0, stream>>>(part, (float*)d_out);
}

// Round 8
// 380.671 us; speedup vs baseline: 1.7227x; 1.7227x over previous
//
#include <hip/hip_runtime.h>

typedef unsigned short u16;
typedef unsigned int   u32;
typedef __bf16 bf16x8 __attribute__((ext_vector_type(8)));
typedef u16    u16x8  __attribute__((ext_vector_type(8)));
typedef float  f32x4  __attribute__((ext_vector_type(4)));

#define DI static __device__ __forceinline__

DI float b2f(u16 u){ union { u32 i; float f; } c; c.i = ((u32)u) << 16; return c.f; }
DI u16 f2b(float f){ return __builtin_bit_cast(u16, (__bf16)f); }   // HW RNE cvt
DI float eluf(float x){ return x > 0.f ? x : (__expf(x) - 1.f); }
DI float sigf(float x){ return 1.f / (1.f + __expf(-x)); }
DI f32x4 mfma16(bf16x8 a, bf16x8 b, f32x4 c){
  return __builtin_amdgcn_mfma_f32_16x16x32_bf16(a, b, c, 0, 0, 0);
}
DI bf16x8 ldb(const u16* p){ return *(const bf16x8*)p; }

// ---------------------------------------------------------------------------
// k_pack: blocks 0..1023 pack x (LDS-staged, coalesced both sides);
// blocks 1024..1376 pack weights via LDS-staged 32x256 tiles (coalesced
// float4 reads).  Fragment layout (all):
//   elem = W[k=kc*32+(lane>>4)*8+j][n=nb*16+(lane&15)]
// ---------------------------------------------------------------------------
DI void stage_tile(const float* __restrict__ W, int t, u16* sT){
  #pragma unroll
  for (int u = 0; u < 8; u++){
    int c = u * 256 + t, row = c >> 6, colf = (c & 63) * 4;
    float4 v4 = *(const float4*)&W[row * 256 + colf];
    u16 a = f2b(v4.x), b = f2b(v4.y), cc = f2b(v4.z), d = f2b(v4.w);
    uint2 pk; pk.x = (u32)a | ((u32)b << 16); pk.y = (u32)cc | ((u32)d << 16);
    *(uint2*)&sT[row * 260 + colf] = pk;
  }
}
DI void emit_tile(const u16* sT, int t, u16* dstbase, int kc, int KC){
  #pragma unroll
  for (int u = 0; u < 4; u++){
    int g = u * 256 + t, nb = g >> 6, lane = g & 63, ln = lane & 15, q = lane >> 4;
    u16x8 tv;
    #pragma unroll
    for (int j = 0; j < 8; j++) tv[j] = sT[(q * 8 + j) * 260 + nb * 16 + ln];
    *(uint4*)&dstbase[((size_t)(nb * KC + kc)) * 512 + lane * 8] = __builtin_bit_cast(uint4, tv);
  }
}

__global__ __launch_bounds__(256) void k_pack(
    const float* __restrict__ x,
    const float* __restrict__ wfc1, const float* __restrict__ wskip,
    const float* __restrict__ vfc1, const float* __restrict__ vfc2,
    const float* __restrict__ vgate, const float* __restrict__ vskip,
    u16* __restrict__ pX, u16* __restrict__ pW1, u16* __restrict__ pF1,
    u16* __restrict__ pSk, u16* __restrict__ pF2, u16* __restrict__ pGa)
{
  __shared__ u16 sX[16 * 1032];     // 33024 B; also used as tile/skip stage
  const int t = threadIdx.x;
  if (blockIdx.x < 1024){
    const int rb = blockIdx.x;
    const float* xp = x + (size_t)rb * 16384;
    #pragma unroll
    for (int it = 0; it < 16; it++){
      float4 v4 = *(const float4*)&xp[it * 1024 + t * 4];
      u16 t0 = f2b(v4.x), t1 = f2b(v4.y), t2 = f2b(v4.z), t3 = f2b(v4.w);
      uint2 pk; pk.x = (u32)t0 | ((u32)t1 << 16); pk.y = (u32)t2 | ((u32)t3 << 16);
      *(uint2*)&sX[it * 1032 + t * 4] = pk;
    }
    __syncthreads();
    u16* dst = pX + (size_t)rb * 16384;
    #pragma unroll
    for (int u = 0; u < 8; u++){
      int c = u * 256 + t;
      int kc = c >> 6, lane = c & 63, ln = lane & 15, q = lane >> 4;
      u16x8 v = *(const u16x8*)&sX[ln * 1032 + kc * 32 + q * 8];
      *(uint4*)&dst[kc * 512 + lane * 8] = __builtin_bit_cast(uint4, v);
    }
    return;
  }
  const int wb = blockIdx.x - 1024;   // 0..352
  if (wb == 32){
    // wskip [1024][16] -> pW1 nb=16 (kc 0..31)
    #pragma unroll
    for (int u = 0; u < 64; u++){
      int c = u * 256 + t, row = c >> 2, colf = (c & 3) * 4;
      float4 v4 = *(const float4*)&wskip[row * 16 + colf];
      u16 a = f2b(v4.x), b = f2b(v4.y), cc = f2b(v4.z), d = f2b(v4.w);
      uint2 pk; pk.x = (u32)a | ((u32)b << 16); pk.y = (u32)cc | ((u32)d << 16);
      *(uint2*)&sX[row * 16 + colf] = pk;
    }
    __syncthreads();
    #pragma unroll
    for (int u = 0; u < 8; u++){
      int g = u * 256 + t, kc = g >> 6, lane = g & 63, ln = lane & 15, q = lane >> 4;
      u16x8 tv;
      #pragma unroll
      for (int j = 0; j < 8; j++) tv[j] = sX[(kc * 32 + q * 8 + j) * 16 + ln];
      *(uint4*)&pW1[((size_t)(16 * 32 + kc)) * 512 + lane * 8] = __builtin_bit_cast(uint4, tv);
    }
    return;
  }
  const float* src; u16* dstbase; int kc, KC;
  if (wb < 32){                       // wfc1 [1024][256] -> pW1 nb 0..15
    kc = wb; KC = 32; src = wfc1 + (size_t)kc * 32 * 256; dstbase = pW1;
  } else if (wb < 65){                // vfc1 [16][64][256] -> pF1
    int idx = wb - 33, v = idx >> 1, ks = idx & 1;
    kc = ks; KC = 2; src = vfc1 + ((size_t)v * 64 + ks * 32) * 256;
    dstbase = pF1 + (size_t)v * 32 * 512;
  } else if (wb < 97){                // vskip -> pSk
    int idx = wb - 65, v = idx >> 1, ks = idx & 1;
    kc = ks; KC = 2; src = vskip + ((size_t)v * 64 + ks * 32) * 256;
    dstbase = pSk + (size_t)v * 32 * 512;
  } else if (wb < 225){               // vfc2 [16][256][256] -> pF2
    int idx = wb - 97, v = idx >> 3, kk = idx & 7;
    kc = kk; KC = 8; src = vfc2 + ((size_t)v * 256 + kk * 32) * 256;
    dstbase = pF2 + (size_t)v * 128 * 512;
  } else {                            // vgate -> pGa
    int idx = wb - 225, v = idx >> 3, kk = idx & 7;
    kc = kk; KC = 8; src = vgate + ((size_t)v * 256 + kk * 32) * 256;
    dstbase = pGa + (size_t)v * 128 * 512;
  }
  stage_tile(src, t, sX);
  __syncthreads();
  emit_tile(sX, t, dstbase, kc, KC);
}

// ---------------------------------------------------------------------------
// Fused kernel: weight-GRN prologue (w -> sWt, duplicated per v-half) +
// 2-barrier v-loop over HALF the variables.
// Grid 1024: xcd = bid&7; vhalf = xcd>>2; rowblk = (bid>>3)*4 + (bid&3).
//  -> XCDs 0-3 run v 0..7, XCDs 4-7 run v 8..15: per-XCD weight working set
//     = pW1(1.1MB) + half weights(2.65MB) = 3.75MB <= 4MB L2.
// vhalf 0 -> plain store to part (ws); vhalf 1 -> plain store to out;
// k_reduce then does out += part. No atomics anywhere.
// LDS 35840 B -> 4 blocks/CU by LDS; __launch_bounds__(512,4) (NOT 8:
// round 7 proved the 8-wave ask caps VGPR at 32 -> total spill, 1.2GB
// scratch WRITE). (512,4) -> 128 VGPR cap, compiles to ~64, no spill, and
// the 1024-block grid fills 4 blocks/CU.
// ---------------------------------------------------------------------------
__global__ __launch_bounds__(512, 4) void k_fused(
    const u16* __restrict__ pX, const u16* __restrict__ pW1,
    const u16* __restrict__ pF1, const u16* __restrict__ pSk,
    const u16* __restrict__ pF2, const u16* __restrict__ pGa,
    const float* __restrict__ wb1, const float* __restrict__ W2,
    const float* __restrict__ wb2, const float* __restrict__ Wg,
    const float* __restrict__ wbg, const float* __restrict__ wbs,
    const float* __restrict__ b1, const float* __restrict__ b2,
    const float* __restrict__ bg, const float* __restrict__ bs,
    float* __restrict__ part, float* __restrict__ out)
{
  __shared__ __align__(16) char smem[35840];
  u16*   sHh = (u16*)smem;                     // 16896: prologue h / v-loop hv
  u16*   sHy = (u16*)(smem + 16896);           // 16896: v-loop yv
  // prologue aliases inside sHy region:
  u16*   sW2 = (u16*)(smem + 16896);           // 8192: W2 bf16 [256][16]
  float* sR  = (float*)(smem + 16896 + 8192);  // 2048
  float* sY  = (float*)(smem + 16896 + 10240); // 2048
  float* sWg = (float*)(smem + 16896 + 12288); // 1024
  float* sWt = (float*)(smem + 33792);         // 2048, persists

  const int tid  = threadIdx.x;
  const int lane = tid & 63;
  const int wid  = tid >> 6;
  const int ln   = lane & 15;
  const int q    = lane >> 4;
  const int bid  = blockIdx.x;
  const int xcd  = bid & 7;
  const int vhalf = xcd >> 2;                  // XCD-partitioned v-half
  const int rowblk = (bid >> 3) * 4 + (bid & 3);
  const int row0 = rowblk * 32;
  const int rb0  = rowblk * 2;
  const int nb0  = wid * 2;
  const int v0   = vhalf * 8;

  // ===================== prologue: weight GRN -> sWt =====================
  {
    const int ncnt = (wid == 7) ? 3 : 2;
    // stage W2 bf16 + Wg fp32
    {
      const float* wp = &W2[tid * 8];
      float4 lo = *(const float4*)wp, hi = *(const float4*)(wp + 4);
      u16x8 tv;
      tv[0]=f2b(lo.x); tv[1]=f2b(lo.y); tv[2]=f2b(lo.z); tv[3]=f2b(lo.w);
      tv[4]=f2b(hi.x); tv[5]=f2b(hi.y); tv[6]=f2b(hi.z); tv[7]=f2b(hi.w);
      *(uint4*)&sW2[tid * 8] = __builtin_bit_cast(uint4, tv);
      if (tid < 256) sWg[tid] = Wg[tid];
    }

    f32x4 acc[2][3];
    #pragma unroll
    for (int mb = 0; mb < 2; mb++)
      #pragma unroll
      for (int i = 0; i < 3; i++){ acc[mb][i][0]=0.f; acc[mb][i][1]=0.f; acc[mb][i][2]=0.f; acc[mb][i][3]=0.f; }

    for (int kc = 0; kc < 32; kc++){
      bf16x8 a[2];
      #pragma unroll
      for (int mb = 0; mb < 2; mb++)
        a[mb] = ldb(&pX[((size_t)(rb0 + mb) * 32 + kc) * 512 + lane * 8]);
      #pragma unroll
      for (int i = 0; i < 3; i++){
        if (i < ncnt){
          bf16x8 b = ldb(&pW1[(size_t)((nb0 + i) * 32 + kc) * 512 + lane * 8]);
          #pragma unroll
          for (int mb = 0; mb < 2; mb++) acc[mb][i] = mfma16(a[mb], b, acc[mb][i]);
        }
      }
    }

    #pragma unroll
    for (int i = 0; i < 3; i++){
      if (i < ncnt){
        int nb = nb0 + i;
        int col = nb * 16 + ln;
        float vb = (nb < 16) ? wb1[col] : wbs[ln];
        #pragma unroll
        for (int mb = 0; mb < 2; mb++){
          #pragma unroll
          for (int r = 0; r < 4; r++){
            int lr = mb * 16 + q * 4 + r;
            float v = acc[mb][i][r] + vb;
            if (nb < 16) sHh[lr * 264 + col] = f2b(eluf(v));
            else         sR[lr * 16 + ln] = v;
          }
        }
      }
    }
    __syncthreads();

    // y = h @ W2 + b2  (W2 bf16 in LDS)
    {
      int r = tid >> 4, j = tid & 15;
      float a0 = wb2[j];
      #pragma unroll 4
      for (int kb = 0; kb < 32; kb++){
        u16x8 h8 = *(const u16x8*)&sHh[r * 264 + kb * 8];
        #pragma unroll
        for (int u = 0; u < 8; u++)
          a0 += b2f(h8[u]) * b2f(sW2[(kb * 8 + u) * 16 + j]);
      }
      sY[r * 16 + j] = a0;
    }
    __syncthreads();

    // gate = sigmoid(y @ Wg + bg) -> sWt (scratch)
    {
      int r = tid >> 4, j = tid & 15;
      float g0 = wbg[j];
      #pragma unroll
      for (int k = 0; k < 16; k++)
        g0 += sY[r * 16 + k] * sWg[k * 16 + j];
      sWt[r * 16 + j] = sigf(g0);
    }
    __syncthreads();

    // softmax over 16 -> sWt
    if (tid < 32){
      int r = tid;
      float l[16]; float m = -1e30f;
      #pragma unroll
      for (int j = 0; j < 16; j++){
        float v = sR[r * 16 + j] + sWt[r * 16 + j] * sY[r * 16 + j];
        l[j] = v; m = fmaxf(m, v);
      }
      float s = 0.f;
      #pragma unroll
      for (int j = 0; j < 16; j++){ l[j] = __expf(l[j] - m); s += l[j]; }
      float inv = 1.f / s;
      #pragma unroll
      for (int j = 0; j < 16; j++) sWt[r * 16 + j] = l[j] * inv;
    }
    __syncthreads();
  }

  // ===================== v-loop over this block's 8 variables =====================
  f32x4 z[2][2];
  #pragma unroll
  for (int mb = 0; mb < 2; mb++)
    #pragma unroll
    for (int i = 0; i < 2; i++){ z[mb][i][0]=0.f; z[mb][i][1]=0.f; z[mb][i][2]=0.f; z[mb][i][3]=0.f; }

  #pragma unroll 1
  for (int vi = 0; vi < 8; vi++){
    const int v = v0 + vi;
    bf16x8 a0[2], a1[2];
    #pragma unroll
    for (int mb = 0; mb < 2; mb++){
      const u16* xp = &pX[((size_t)(rb0 + mb) * 32 + v * 2) * 512 + lane * 8];
      a0[mb] = ldb(xp);
      a1[mb] = ldb(xp + 512);
    }
    float wv[2][4];
    #pragma unroll
    for (int mb = 0; mb < 2; mb++)
      #pragma unroll
      for (int r = 0; r < 4; r++) wv[mb][r] = sWt[(mb * 16 + q * 4 + r) * 16 + v];

    // ---- phase 1a: hv = elu(Xv @ W1v + b1) -> sHh
    f32x4 hacc[2][2];
    #pragma unroll
    for (int mb = 0; mb < 2; mb++)
      #pragma unroll
      for (int i = 0; i < 2; i++){ hacc[mb][i][0]=0.f; hacc[mb][i][1]=0.f; hacc[mb][i][2]=0.f; hacc[mb][i][3]=0.f; }
    #pragma unroll
    for (int ks = 0; ks < 2; ks++){
      bf16x8 B0 = ldb(&pF1[(size_t)((v * 16 + nb0) * 2 + ks) * 512 + lane * 8]);
      bf16x8 B1 = ldb(&pF1[(size_t)((v * 16 + nb0 + 1) * 2 + ks) * 512 + lane * 8]);
      #pragma unroll
      for (int mb = 0; mb < 2; mb++){
        bf16x8 a = ks ? a1[mb] : a0[mb];
        hacc[mb][0] = mfma16(a, B0, hacc[mb][0]);
        hacc[mb][1] = mfma16(a, B1, hacc[mb][1]);
      }
    }
    #pragma unroll
    for (int i = 0; i < 2; i++){
      int col = (nb0 + i) * 16 + ln;
      float vb = b1[v * 256 + col];
      #pragma unroll
      for (int mb = 0; mb < 2; mb++)
        #pragma unroll
        for (int r = 0; r < 4; r++)
          sHh[(mb * 16 + q * 4 + r) * 264 + col] = f2b(eluf(hacc[mb][i][r] + vb));
    }

    // ---- phase 1b: rv = Xv @ Wsv + bs ; z += wv * rv
    f32x4 racc[2][2];
    #pragma unroll
    for (int mb = 0; mb < 2; mb++)
      #pragma unroll
      for (int i = 0; i < 2; i++){ racc[mb][i][0]=0.f; racc[mb][i][1]=0.f; racc[mb][i][2]=0.f; racc[mb][i][3]=0.f; }
    #pragma unroll
    for (int ks = 0; ks < 2; ks++){
      bf16x8 B0 = ldb(&pSk[(size_t)((v * 16 + nb0) * 2 + ks) * 512 + lane * 8]);
      bf16x8 B1 = ldb(&pSk[(size_t)((v * 16 + nb0 + 1) * 2 + ks) * 512 + lane * 8]);
      #pragma unroll
      for (int mb = 0; mb < 2; mb++){
        bf16x8 a = ks ? a1[mb] : a0[mb];
        racc[mb][0] = mfma16(a, B0, racc[mb][0]);
        racc[mb][1] = mfma16(a, B1, racc[mb][1]);
      }
    }
    #pragma unroll
    for (int i = 0; i < 2; i++){
      float vb = bs[v * 256 + (nb0 + i) * 16 + ln];
      #pragma unroll
      for (int mb = 0; mb < 2; mb++)
        #pragma unroll
        for (int r = 0; r < 4; r++) z[mb][i][r] += wv[mb][r] * (racc[mb][i][r] + vb);
    }
    __syncthreads();   // B1: hv visible; prev-v yv reads done before sHy rewrite

    // ---- phase 2: yv = hv @ W2v + b2  (read sHh, write sHy)
    f32x4 yacc[2][2];
    #pragma unroll
    for (int mb = 0; mb < 2; mb++)
      #pragma unroll
      for (int i = 0; i < 2; i++){ yacc[mb][i][0]=0.f; yacc[mb][i][1]=0.f; yacc[mb][i][2]=0.f; yacc[mb][i][3]=0.f; }
    #pragma unroll
    for (int kc = 0; kc < 8; kc++){
      bf16x8 B0 = ldb(&pF2[(size_t)((v * 16 + nb0) * 8 + kc) * 512 + lane * 8]);
      bf16x8 B1 = ldb(&pF2[(size_t)((v * 16 + nb0 + 1) * 8 + kc) * 512 + lane * 8]);
      #pragma unroll
      for (int mb = 0; mb < 2; mb++){
        bf16x8 ah = *(const bf16x8*)&sHh[(mb * 16 + ln) * 264 + kc * 32 + q * 8];
        yacc[mb][0] = mfma16(ah, B0, yacc[mb][0]);
        yacc[mb][1] = mfma16(ah, B1, yacc[mb][1]);
      }
    }
    f32x4 ysave[2][2];
    #pragma unroll
    for (int i = 0; i < 2; i++){
      int col = (nb0 + i) * 16 + ln;
      float vb = b2[v * 256 + col];
      #pragma unroll
      for (int mb = 0; mb < 2; mb++)
        #pragma unroll
        for (int r = 0; r < 4; r++){
          float yy = yacc[mb][i][r] + vb;
          ysave[mb][i][r] = yy;
          sHy[(mb * 16 + q * 4 + r) * 264 + col] = f2b(yy);
        }
    }
    __syncthreads();   // B2: yv visible; all hv reads done before next-v rewrite

    // ---- phase 3: gv = sigmoid(yv @ Wgv + bg); z += wv * gv * yv
    f32x4 gacc[2][2];
    #pragma unroll
    for (int mb = 0; mb < 2; mb++)
      #pragma unroll
      for (int i = 0; i < 2; i++){ gacc[mb][i][0]=0.f; gacc[mb][i][1]=0.f; gacc[mb][i][2]=0.f; gacc[mb][i][3]=0.f; }
    #pragma unroll
    for (int kc = 0; kc < 8; kc++){
      bf16x8 B0 = ldb(&pGa[(size_t)((v * 16 + nb0) * 8 + kc) * 512 + lane * 8]);
      bf16x8 B1 = ldb(&pGa[(size_t)((v * 16 + nb0 + 1) * 8 + kc) * 512 + lane * 8]);
      #pragma unroll
      for (int mb = 0; mb < 2; mb++){
        bf16x8 ah = *(const bf16x8*)&sHy[(mb * 16 + ln) * 264 + kc * 32 + q * 8];
        gacc[mb][0] = mfma16(ah, B0, gacc[mb][0]);
        gacc[mb][1] = mfma16(ah, B1, gacc[mb][1]);
      }
    }
    #pragma unroll
    for (int i = 0; i < 2; i++){
      float vb = bg[v * 256 + (nb0 + i) * 16 + ln];
      #pragma unroll
      for (int mb = 0; mb < 2; mb++)
        #pragma unroll
        for (int r = 0; r < 4; r++)
          z[mb][i][r] += wv[mb][r] * sigf(gacc[mb][i][r] + vb) * ysave[mb][i][r];
    }
  }

  // store partial z: vhalf 0 -> part (ws), vhalf 1 -> out. Plain stores.
  float* dst = vhalf ? out : part;
  #pragma unroll
  for (int i = 0; i < 2; i++){
    int col = (nb0 + i) * 16 + ln;
    #pragma unroll
    for (int mb = 0; mb < 2; mb++)
      #pragma unroll
      for (int r = 0; r < 4; r++)
        dst[(size_t)(row0 + mb * 16 + q * 4 + r) * 256 + col] = z[mb][i][r];
  }
}

// ---------------------------------------------------------------------------
// k_reduce: out += part  (4,194,304 floats; 4096 blocks x 256 thr x float4)
// ---------------------------------------------------------------------------
__global__ __launch_bounds__(256) void k_reduce(
    const float* __restrict__ part, float* __restrict__ out)
{
  size_t i = ((size_t)blockIdx.x * 256 + threadIdx.x) * 4;
  float4 a = *(const float4*)&part[i];
  float4 b = *(const float4*)&out[i];
  b.x += a.x; b.y += a.y; b.z += a.z; b.w += a.w;
  *(float4*)&out[i] = b;
}

// ---------------------------------------------------------------------------
extern "C" void kernel_launch(void* const* d_in, const int* in_sizes, int n_in,
                              void* d_out, int out_size, void* d_ws, size_t ws_size,
                              hipStream_t stream)
{
  const float* x     = (const float*)d_in[0];
  const float* wfc1w = (const float*)d_in[1];
  const float* wfc1b = (const float*)d_in[2];
  const float* wfc2w = (const float*)d_in[3];
  const float* wfc2b = (const float*)d_in[4];
  const float* wgw   = (const float*)d_in[5];
  const float* wgb   = (const float*)d_in[6];
  const float* wsw   = (const float*)d_in[7];
  const float* wsb   = (const float*)d_in[8];
  const float* vfc1w = (const float*)d_in[9];
  const float* vfc1b = (const float*)d_in[10];
  const float* vfc2w = (const float*)d_in[11];
  const float* vfc2b = (const float*)d_in[12];
  const float* vgw   = (const float*)d_in[13];
  const float* vgb   = (const float*)d_in[14];
  const float* vsw   = (const float*)d_in[15];
  const float* vsb   = (const float*)d_in[16];

  u16* ws   = (u16*)d_ws;
  u16* pX   = ws;                      // 16777216 u16 (32 MB)
  u16* pW1  = pX + 16777216;           // 278528 u16
  u16* pF1  = pW1 + 278528;            // 262144
  u16* pSk  = pF1 + 262144;            // 262144
  u16* pF2  = pSk + 262144;            // 1048576
  u16* pGa  = pF2 + 1048576;           // 1048576
  float* part = (float*)(pGa + 1048576); // 4194304 fp32 (16 MB)

  k_pack<<<dim3(1377), dim3(256), 0, stream>>>(
      x, wfc1w, wsw, vfc1w, vfc2w, vgw, vsw, pX, pW1, pF1, pSk, pF2, pGa);

  k_fused<<<dim3(1024), dim3(512), 0, stream>>>(
      pX, pW1, pF1, pSk, pF2, pGa,
      wfc1b, wfc2w, wfc2b, wgw, wgb, wsb,
      vfc1b, vfc2b, vgb, vsb, part, (float*)d_out);

  k_reduce<<<dim3(4096), dim3(256), 0, stream>>>(part, (float*)d_out);
}